// Round 6
// baseline (381.857 us; speedup 1.0000x reference)
//
#include <hip/hip_runtime.h>
#include <hip/hip_bf16.h>

#define CHUNK 1024
#define BINCAP 320
typedef unsigned int uint;
typedef unsigned short ushort;

// ---------- Phase 0: single-pass partition into 8 dst-ranges + degree hist ----------
// LDS multisplit: bins of (src,dst) pairs flushed in ~1KB contiguous chunks with one
// global cursor atomic per bin per round. Degree hist fused (all lanes active).
__global__ __launch_bounds__(256) void partition_hist(const int* __restrict__ src,
                                                      const int* __restrict__ dst,
                                                      int* __restrict__ deg,
                                                      int* __restrict__ gcur,
                                                      int2* __restrict__ staging,
                                                      int cap, int nE, int N) {
    __shared__ int2 bins[8][BINCAP];
    __shared__ int cnt[8];
    __shared__ int res[8];
    const int t  = threadIdx.x;
    const int nb = gridDim.x;
    const int rounds = (nE + nb * 1024 - 1) / (nb * 1024);

    for (int rd = 0; rd < rounds; ++rd) {
        if (t < 8) cnt[t] = 0;
        __syncthreads();

        const int e4 = (rd * nb + blockIdx.x) * 1024 + t * 4;
        int s[4], d[4];
        int nv = 0;
        if (e4 + 3 < nE) {
            const int4 s4 = *reinterpret_cast<const int4*>(src + e4);
            const int4 d4 = *reinterpret_cast<const int4*>(dst + e4);
            s[0] = s4.x; s[1] = s4.y; s[2] = s4.z; s[3] = s4.w;
            d[0] = d4.x; d[1] = d4.y; d[2] = d4.z; d[3] = d4.w;
            nv = 4;
        } else {
            for (int e = e4; e < nE; ++e) { s[nv] = src[e]; d[nv] = dst[e]; ++nv; }
        }
#pragma unroll
        for (int i = 0; i < 4; ++i) {
            if (i < nv) {
                const int r = (int)(((long long)d[i] * 8) / N);
                const int pos = atomicAdd(&cnt[r], 1);
                if (pos < BINCAP) {
                    bins[r][pos] = make_int2(s[i], d[i]);
                } else {  // statistically-impossible overflow: direct global append
                    const int gp = atomicAdd(&gcur[r], 1);
                    staging[(size_t)r * cap + gp] = make_int2(s[i], d[i]);
                }
                atomicAdd(&deg[d[i]], 1);
            }
        }
        __syncthreads();
        if (t < 8) {
            int c = cnt[t];
            c = c < BINCAP ? c : BINCAP;
            cnt[t] = c;
            res[t] = (c > 0) ? atomicAdd(&gcur[t], c) : 0;
        }
        __syncthreads();
#pragma unroll
        for (int r = 0; r < 8; ++r) {
            const int c = cnt[r];
            const int b = res[r];
            for (int i = t; i < c; i += 256)
                staging[(size_t)r * cap + b + i] = bins[r][i];
        }
        __syncthreads();
    }
}

// ---------- Phase B2: bucket from compacted range list (all lanes active) ----------
__global__ __launch_bounds__(256) void bucket_range(const int2* __restrict__ staging,
                                                    const int* __restrict__ gcur,
                                                    int* __restrict__ cur,
                                                    int* __restrict__ csr, int cap) {
    const int r = blockIdx.x & 7;   // XCD-aligned: one range's cur/csr slice per L2
    const int g = blockIdx.x >> 3;
    const int G = gridDim.x >> 3;
    const int cnt = gcur[r];
    const int2* ep = staging + (size_t)r * cap;
    const int tid = g * 256 + (int)threadIdx.x;
    const int stride = G * 256 * 2;
    for (int i = tid * 2; i < cnt; i += stride) {
        if (i + 1 < cnt) {
            const int4 two = *reinterpret_cast<const int4*>(ep + i);  // (s0,d0,s1,d1)
            const int p0 = atomicAdd(&cur[two.y], 1);
            const int p1 = atomicAdd(&cur[two.w], 1);
            csr[p0] = two.x;
            csr[p1] = two.z;
        } else {
            const int2 p = ep[i];
            const int pos = atomicAdd(&cur[p.y], 1);
            csr[pos] = p.x;
        }
    }
}

// ---------- scans ----------
__global__ __launch_bounds__(256) void scan_chunks(const int* __restrict__ deg,
                                                   int* __restrict__ off,
                                                   int* __restrict__ partials, int N) {
    __shared__ int sums[256];
    const int b = blockIdx.x, t = threadIdx.x;
    const int base = b * CHUNK + t * 4;
    int v[4];
#pragma unroll
    for (int i = 0; i < 4; ++i) v[i] = (base + i < N) ? deg[base + i] : 0;
    const int s = v[0] + v[1] + v[2] + v[3];
    sums[t] = s;
    __syncthreads();
    for (int d = 1; d < 256; d <<= 1) {
        int x = (t >= d) ? sums[t - d] : 0;
        __syncthreads();
        sums[t] += x;
        __syncthreads();
    }
    const int excl = sums[t] - s;
    if (t == 255) partials[b] = sums[255];
    int run = excl;
#pragma unroll
    for (int i = 0; i < 4; ++i) {
        if (base + i < N) off[base + i] = run;
        run += v[i];
    }
}

__global__ __launch_bounds__(256) void scan_partials(int* partials, int P) {
    __shared__ int buf[256];
    const int t = threadIdx.x;
    if (P <= 256) {
        const int v = (t < P) ? partials[t] : 0;
        buf[t] = v;
        __syncthreads();
        for (int d = 1; d < 256; d <<= 1) {
            int x = (t >= d) ? buf[t - d] : 0;
            __syncthreads();
            buf[t] += x;
            __syncthreads();
        }
        if (t < P) partials[t] = buf[t] - v;  // exclusive
    } else if (t == 0) {
        int acc = 0;
        for (int i = 0; i < P; ++i) { int v = partials[i]; partials[i] = acc; acc += v; }
    }
}

__global__ void add_base(int* __restrict__ off, int* __restrict__ cur,
                         const int* __restrict__ partials, int N) {
    int i = blockIdx.x * blockDim.x + threadIdx.x;
    if (i < N) {
        int o = off[i] + partials[i >> 10];
        off[i] = o;
        cur[i] = o;
    }
}

// ---------- Phase A: h = feat @ W, output bf16 ----------
__global__ __launch_bounds__(256) void gemm_h(const float* __restrict__ feat,
                                              const float* __restrict__ weight,
                                              ushort* __restrict__ h, int M) {
    __shared__ float As[64][68];
    __shared__ float Wc[64][128];
    const int t  = threadIdx.x;
    const int tx = t & 15;
    const int ty = t >> 4;
    const int row0 = blockIdx.x * 64;

    float acc[4][8];
#pragma unroll
    for (int i = 0; i < 4; ++i)
#pragma unroll
        for (int j = 0; j < 8; ++j) acc[i][j] = 0.0f;

    for (int c = 0; c < 2; ++c) {
        if (c) __syncthreads();
        {
            const int k4 = (t & 15) * 4;
            const int rbase = t >> 4;
#pragma unroll
            for (int p = 0; p < 4; ++p) {
                const int rr = rbase + p * 16;
                const int grow = row0 + rr;
                float4 v = make_float4(0.f, 0.f, 0.f, 0.f);
                if (grow < M)
                    v = *reinterpret_cast<const float4*>(&feat[(size_t)grow * 128 + c * 64 + k4]);
                *reinterpret_cast<float4*>(&As[rr][k4]) = v;
            }
        }
        {
#pragma unroll
            for (int p = 0; p < 8; ++p) {
                const int idx = (p * 256 + t) * 4;
                const int kk = idx >> 7;
                const int j = idx & 127;
                *reinterpret_cast<float4*>(&Wc[kk][j]) =
                    *reinterpret_cast<const float4*>(&weight[(c * 64 + kk) * 128 + j]);
            }
        }
        __syncthreads();

#pragma unroll 8
        for (int k = 0; k < 64; ++k) {
            float a[4];
#pragma unroll
            for (int i = 0; i < 4; ++i) a[i] = As[ty * 4 + i][k];
            const float4 b0 = *reinterpret_cast<const float4*>(&Wc[k][tx * 8 + 0]);
            const float4 b1 = *reinterpret_cast<const float4*>(&Wc[k][tx * 8 + 4]);
            const float b[8] = {b0.x, b0.y, b0.z, b0.w, b1.x, b1.y, b1.z, b1.w};
#pragma unroll
            for (int i = 0; i < 4; ++i)
#pragma unroll
                for (int j = 0; j < 8; ++j)
                    acc[i][j] = fmaf(a[i], b[j], acc[i][j]);
        }
    }

#pragma unroll
    for (int i = 0; i < 4; ++i) {
        const int grow = row0 + ty * 4 + i;
        if (grow < M) {
            union { ushort u16[8]; uint4 v; } pk;
#pragma unroll
            for (int j = 0; j < 8; ++j) {
                const uint u = __float_as_uint(acc[i][j]);
                pk.u16[j] = (ushort)((u + 0x7fffu + ((u >> 16) & 1u)) >> 16);  // RNE to bf16
            }
            *reinterpret_cast<uint4*>(&h[(size_t)grow * 128 + tx * 8]) = pk.v;
        }
    }
}

// ---------- Phase B: out[n] = (sum h[s]) * rsqrt(max(deg,1)) + bias ----------
__global__ __launch_bounds__(256) void aggregate_h(const ushort* __restrict__ h,
                                                   const int* __restrict__ csr,
                                                   const int* __restrict__ off,
                                                   const int* __restrict__ deg,
                                                   const float* __restrict__ bias,
                                                   float* __restrict__ out, int N) {
    const int node = (blockIdx.x * blockDim.x + threadIdx.x) >> 6;
    if (node >= N) return;
    const int lane = threadIdx.x & 63;
    const int half = lane >> 5;
    const int sub  = lane & 31;
    const int start = off[node];
    const int cnt   = deg[node];
    const int end   = start + cnt;

    float ax = 0.f, ay = 0.f, az = 0.f, aw = 0.f;

    int j = start;
    for (; j + 15 < end; j += 16) {
        int s[8];
#pragma unroll
        for (int k = 0; k < 8; ++k) s[k] = csr[j + 2 * k + half];
        uint2 r[8];
#pragma unroll
        for (int k = 0; k < 8; ++k)
            r[k] = *reinterpret_cast<const uint2*>(h + (size_t)s[k] * 128 + sub * 4);
#pragma unroll
        for (int k = 0; k < 8; ++k) {
            ax += __uint_as_float((r[k].x & 0xffffu) << 16);
            ay += __uint_as_float(r[k].x & 0xffff0000u);
            az += __uint_as_float((r[k].y & 0xffffu) << 16);
            aw += __uint_as_float(r[k].y & 0xffff0000u);
        }
    }
    for (; j + 7 < end; j += 8) {
        int s[4];
#pragma unroll
        for (int k = 0; k < 4; ++k) s[k] = csr[j + 2 * k + half];
        uint2 r[4];
#pragma unroll
        for (int k = 0; k < 4; ++k)
            r[k] = *reinterpret_cast<const uint2*>(h + (size_t)s[k] * 128 + sub * 4);
#pragma unroll
        for (int k = 0; k < 4; ++k) {
            ax += __uint_as_float((r[k].x & 0xffffu) << 16);
            ay += __uint_as_float(r[k].x & 0xffff0000u);
            az += __uint_as_float((r[k].y & 0xffffu) << 16);
            aw += __uint_as_float(r[k].y & 0xffff0000u);
        }
    }
    for (j += half; j < end; j += 2) {
        const int s = csr[j];
        const uint2 r = *reinterpret_cast<const uint2*>(h + (size_t)s * 128 + sub * 4);
        ax += __uint_as_float((r.x & 0xffffu) << 16);
        ay += __uint_as_float(r.x & 0xffff0000u);
        az += __uint_as_float((r.y & 0xffffu) << 16);
        aw += __uint_as_float(r.y & 0xffff0000u);
    }

    ax += __shfl_xor(ax, 32, 64);
    ay += __shfl_xor(ay, 32, 64);
    az += __shfl_xor(az, 32, 64);
    aw += __shfl_xor(aw, 32, 64);

    if (half == 0) {
        const float nm = rsqrtf(fmaxf((float)cnt, 1.0f));
        const float4 b = *reinterpret_cast<const float4*>(bias + sub * 4);
        float4 o;
        o.x = fmaf(ax, nm, b.x);
        o.y = fmaf(ay, nm, b.y);
        o.z = fmaf(az, nm, b.z);
        o.w = fmaf(aw, nm, b.w);
        *reinterpret_cast<float4*>(out + (size_t)node * 128 + sub * 4) = o;
    }
}

// ---------- Fallback path (ws too small) ----------
__global__ void hist_simple(const int* __restrict__ dst, int* __restrict__ deg, int nE) {
    int e = blockIdx.x * blockDim.x + threadIdx.x;
    if (e < nE) atomicAdd(&deg[dst[e]], 1);
}
__global__ void bucket_simple(const int* __restrict__ src, const int* __restrict__ dst,
                              int* __restrict__ cur, int* __restrict__ csr, int nE) {
    int e = blockIdx.x * blockDim.x + threadIdx.x;
    if (e < nE) {
        int pos = atomicAdd(&cur[dst[e]], 1);
        csr[pos] = src[e];
    }
}
__global__ __launch_bounds__(256) void aggregate_f32(const float* __restrict__ feat,
                                                     const int* __restrict__ csr,
                                                     const int* __restrict__ off,
                                                     const int* __restrict__ deg,
                                                     float* __restrict__ out, int N) {
    const int node = (blockIdx.x * blockDim.x + threadIdx.x) >> 6;
    if (node >= N) return;
    const int lane = threadIdx.x & 63;
    const int start = off[node];
    const int end   = start + deg[node];
    const float2* feat2 = reinterpret_cast<const float2*>(feat);
    float ax = 0.0f, ay = 0.0f;
    for (int j = start; j < end; ++j) {
        const float2 v = feat2[(size_t)csr[j] * 64 + lane];
        ax += v.x;
        ay += v.y;
    }
    reinterpret_cast<float2*>(out)[(size_t)node * 64 + lane] = make_float2(ax, ay);
}
__global__ __launch_bounds__(256) void gemm_norm(const float* agg,
                                                 const float* __restrict__ weight,
                                                 const float* __restrict__ bias,
                                                 const int* __restrict__ deg,
                                                 float* out, int M) {
    __shared__ float As[64][68];
    __shared__ float Wc[64][128];
    const int t  = threadIdx.x;
    const int tx = t & 15;
    const int ty = t >> 4;
    const int row0 = blockIdx.x * 64;
    float acc[4][8];
#pragma unroll
    for (int i = 0; i < 4; ++i)
#pragma unroll
        for (int j = 0; j < 8; ++j) acc[i][j] = 0.0f;
    for (int c = 0; c < 2; ++c) {
        if (c) __syncthreads();
        {
            const int k4 = (t & 15) * 4;
            const int rbase = t >> 4;
#pragma unroll
            for (int p = 0; p < 4; ++p) {
                const int rr = rbase + p * 16;
                const int grow = row0 + rr;
                float4 v = make_float4(0.f, 0.f, 0.f, 0.f);
                if (grow < M)
                    v = *reinterpret_cast<const float4*>(&agg[(size_t)grow * 128 + c * 64 + k4]);
                *reinterpret_cast<float4*>(&As[rr][k4]) = v;
            }
        }
        {
#pragma unroll
            for (int p = 0; p < 8; ++p) {
                const int idx = (p * 256 + t) * 4;
                const int kk = idx >> 7;
                const int j = idx & 127;
                *reinterpret_cast<float4*>(&Wc[kk][j]) =
                    *reinterpret_cast<const float4*>(&weight[(c * 64 + kk) * 128 + j]);
            }
        }
        __syncthreads();
#pragma unroll 8
        for (int k = 0; k < 64; ++k) {
            float a[4];
#pragma unroll
            for (int i = 0; i < 4; ++i) a[i] = As[ty * 4 + i][k];
            const float4 b0 = *reinterpret_cast<const float4*>(&Wc[k][tx * 8 + 0]);
            const float4 b1 = *reinterpret_cast<const float4*>(&Wc[k][tx * 8 + 4]);
            const float b[8] = {b0.x, b0.y, b0.z, b0.w, b1.x, b1.y, b1.z, b1.w};
#pragma unroll
            for (int i = 0; i < 4; ++i)
#pragma unroll
                for (int j = 0; j < 8; ++j)
                    acc[i][j] = fmaf(a[i], b[j], acc[i][j]);
        }
    }
    float bcol[8];
#pragma unroll
    for (int j = 0; j < 8; ++j) bcol[j] = bias[tx * 8 + j];
#pragma unroll
    for (int i = 0; i < 4; ++i) {
        const int grow = row0 + ty * 4 + i;
        if (grow < M) {
            const float nm = rsqrtf(fmaxf((float)deg[grow], 1.0f));
            float4 o0, o1;
            o0.x = fmaf(acc[i][0], nm, bcol[0]);
            o0.y = fmaf(acc[i][1], nm, bcol[1]);
            o0.z = fmaf(acc[i][2], nm, bcol[2]);
            o0.w = fmaf(acc[i][3], nm, bcol[3]);
            o1.x = fmaf(acc[i][4], nm, bcol[4]);
            o1.y = fmaf(acc[i][5], nm, bcol[5]);
            o1.z = fmaf(acc[i][6], nm, bcol[6]);
            o1.w = fmaf(acc[i][7], nm, bcol[7]);
            *reinterpret_cast<float4*>(&out[(size_t)grow * 128 + tx * 8 + 0]) = o0;
            *reinterpret_cast<float4*>(&out[(size_t)grow * 128 + tx * 8 + 4]) = o1;
        }
    }
}

extern "C" void kernel_launch(void* const* d_in, const int* in_sizes, int n_in,
                              void* d_out, int out_size, void* d_ws, size_t ws_size,
                              hipStream_t stream) {
    const float* feat   = (const float*)d_in[0];
    const int*   src    = (const int*)d_in[1];
    const int*   dst    = (const int*)d_in[2];
    const float* weight = (const float*)d_in[3];
    const float* bias   = (const float*)d_in[4];
    float* out = (float*)d_out;

    const int nE = in_sizes[1];
    const int M  = in_sizes[0] / 128;
    const int P  = (M + CHUNK - 1) / CHUNK;

    // ws layout (ints): deg[M] | off[M] | cur[M] | partials[256] | gcur[8] | csr[nE] | staging∪h
    int* degi     = (int*)d_ws;
    int* off      = degi + M;
    int* cur      = off + M;
    int* partials = cur + M;
    int* gcur     = partials + 256;
    int* csr      = gcur + 8;
    const size_t csr_end   = ((size_t)3 * M + 264 + (size_t)nE) * sizeof(int);
    const size_t stage_off = (csr_end + 15) & ~(size_t)15;
    const int cap = (((nE + 7) / 8 + 65536) + 3) & ~3;   // per-range staging capacity (int2)
    int2* staging = (int2*)((char*)d_ws + stage_off);
    ushort* h     = (ushort*)staging;                    // h aliases staging (used after bucket)
    const size_t stage_bytes = (size_t)8 * cap * sizeof(int2);
    const size_t h_bytes     = (size_t)M * 128 * sizeof(ushort);
    const size_t need_big = stage_off + (stage_bytes > h_bytes ? stage_bytes : h_bytes);

    if (ws_size >= need_big) {
        hipMemsetAsync(degi, 0, (size_t)M * sizeof(int), stream);
        hipMemsetAsync(gcur, 0, 8 * sizeof(int), stream);
        partition_hist<<<1024, 256, 0, stream>>>(src, dst, degi, gcur, staging, cap, nE, M);
        scan_chunks<<<P, 256, 0, stream>>>(degi, off, partials, M);
        scan_partials<<<1, 256, 0, stream>>>(partials, P);
        add_base<<<(M + 255) / 256, 256, 0, stream>>>(off, cur, partials, M);
        bucket_range<<<2048, 256, 0, stream>>>(staging, gcur, cur, csr, cap);
        gemm_h<<<(M + 63) / 64, 256, 0, stream>>>(feat, weight, h, M);  // overwrites staging
        aggregate_h<<<(M + 3) / 4, 256, 0, stream>>>(h, csr, off, degi, bias, out, M);
    } else {
        // Minimal-workspace fallback
        hipMemsetAsync(degi, 0, (size_t)M * sizeof(int), stream);
        hist_simple<<<(nE + 255) / 256, 256, 0, stream>>>(dst, degi, nE);
        scan_chunks<<<P, 256, 0, stream>>>(degi, off, partials, M);
        scan_partials<<<1, 256, 0, stream>>>(partials, P);
        add_base<<<(M + 255) / 256, 256, 0, stream>>>(off, cur, partials, M);
        bucket_simple<<<(nE + 255) / 256, 256, 0, stream>>>(src, dst, cur, csr, nE);
        aggregate_f32<<<(M + 3) / 4, 256, 0, stream>>>(feat, csr, off, degi, out, M);
        gemm_norm<<<(M + 63) / 64, 256, 0, stream>>>(out, weight, bias, degi, out, M);
    }
}

// Round 7
// 269.060 us; speedup vs baseline: 1.4192x; 1.4192x over previous
//
#include <hip/hip_runtime.h>
#include <hip/hip_bf16.h>

#define CHUNK 1024
#define RR 64          // dst ranges
#define DEPTH 64       // LDS bin depth (pairs) per range per round
#define WMAX 1600      // max nodes per range (ceil(100000/64)=1563)
typedef unsigned int uint;
typedef unsigned short ushort;

// ---------- Phase 0: single-pass partition into RR dst-ranges ----------
// LDS multisplit of (src,dst) pairs; chunked flush => ~128B contiguous staging
// writes, one gcur atomic per bin per round. NO per-node atomics here.
__global__ __launch_bounds__(256) void partition64(const int* __restrict__ src,
                                                   const int* __restrict__ dst,
                                                   int* __restrict__ gcur,
                                                   int2* __restrict__ staging,
                                                   int cap, int nE, int N) {
    __shared__ int2 bins[RR][DEPTH];
    __shared__ int cnt[RR];
    __shared__ int res[RR];
    const int t  = threadIdx.x;
    const int nb = gridDim.x;
    const int rounds = (nE + nb * 1024 - 1) / (nb * 1024);

    for (int rd = 0; rd < rounds; ++rd) {
        if (t < RR) cnt[t] = 0;
        __syncthreads();

        const int e4 = (rd * nb + blockIdx.x) * 1024 + t * 4;
        int s[4], d[4];
        int nv = 0;
        if (e4 + 3 < nE) {
            const int4 s4 = *reinterpret_cast<const int4*>(src + e4);
            const int4 d4 = *reinterpret_cast<const int4*>(dst + e4);
            s[0] = s4.x; s[1] = s4.y; s[2] = s4.z; s[3] = s4.w;
            d[0] = d4.x; d[1] = d4.y; d[2] = d4.z; d[3] = d4.w;
            nv = 4;
        } else {
            for (int e = e4; e < nE; ++e) { s[nv] = src[e]; d[nv] = dst[e]; ++nv; }
        }
#pragma unroll
        for (int i = 0; i < 4; ++i) {
            if (i < nv) {
                const int r = (int)(((long long)d[i] * RR) / N);
                const int pos = atomicAdd(&cnt[r], 1);
                if (pos < DEPTH) {
                    bins[r][pos] = make_int2(s[i], d[i]);
                } else {  // statistically-negligible overflow: direct global append
                    const int gp = atomicAdd(&gcur[r], 1);
                    staging[(size_t)r * cap + gp] = make_int2(s[i], d[i]);
                }
            }
        }
        __syncthreads();
        if (t < RR) {
            int c = cnt[t];
            c = c < DEPTH ? c : DEPTH;
            cnt[t] = c;
            res[t] = (c > 0) ? atomicAdd(&gcur[t], c) : 0;
        }
        __syncthreads();
        // flush: 4 threads per bin
        {
            const int g = t >> 2;       // bin 0..63
            const int l = t & 3;
            const int c = cnt[g];
            const int b = res[g];
            for (int i = l; i < c; i += 4)
                staging[(size_t)g * cap + b + i] = bins[g][i];
        }
        __syncthreads();
    }
}

// ---------- Phase 1: per-range CSR build entirely in LDS ----------
// One 1024-thread block per range: hist (LDS atomics over <=1563 counters) ->
// deg, LDS scan -> off + cursors, second pass -> csr (LDS cursor atomics only).
__global__ __launch_bounds__(1024) void range_build(const int2* __restrict__ staging,
                                                    const int* __restrict__ gcur,
                                                    int* __restrict__ deg,
                                                    int* __restrict__ off,
                                                    int* __restrict__ csr,
                                                    int cap, int N) {
    __shared__ int hist[WMAX];   // becomes cursors after scan
    __shared__ int sbuf[1024];
    __shared__ int sbase;
    const int r = blockIdx.x;
    const int t = threadIdx.x;
    const int lo = (int)(((long long)r * N + RR - 1) / RR);
    const int hi = (int)(((long long)(r + 1) * N + RR - 1) / RR);
    const int W  = hi - lo;
    const int cnt = gcur[r];

    if (t < RR) sbuf[t] = gcur[t];
    for (int i = t; i < W; i += 1024) hist[i] = 0;
    __syncthreads();
    if (t == 0) {
        int b = 0;
        for (int i = 0; i < r; ++i) b += sbuf[i];
        sbase = b;
    }
    const int2* ep = staging + (size_t)r * cap;
    for (int i = t; i < cnt; i += 1024) {
        const int2 p = ep[i];
        atomicAdd(&hist[p.y - lo], 1);
    }
    __syncthreads();
    const int base = sbase;

    const int i0 = t * 2, i1 = t * 2 + 1;
    const int a = (i0 < W) ? hist[i0] : 0;
    const int b = (i1 < W) ? hist[i1] : 0;
    if (i0 < W) deg[lo + i0] = a;
    if (i1 < W) deg[lo + i1] = b;
    const int tsum = a + b;
    sbuf[t] = tsum;
    __syncthreads();
    for (int dd = 1; dd < 1024; dd <<= 1) {
        const int x = (t >= dd) ? sbuf[t - dd] : 0;
        __syncthreads();
        sbuf[t] += x;
        __syncthreads();
    }
    const int excl = sbuf[t] - tsum;
    if (i0 < W) { off[lo + i0] = base + excl;     hist[i0] = base + excl; }
    if (i1 < W) { off[lo + i1] = base + excl + a; hist[i1] = base + excl + a; }
    __syncthreads();

    for (int i = t; i < cnt; i += 1024) {
        const int2 p = ep[i];
        const int pos = atomicAdd(&hist[p.y - lo], 1);
        csr[pos] = p.x;
    }
}

// ---------- Phase A: h = feat @ W, output bf16 ----------
__global__ __launch_bounds__(256) void gemm_h(const float* __restrict__ feat,
                                              const float* __restrict__ weight,
                                              ushort* __restrict__ h, int M) {
    __shared__ float As[64][68];
    __shared__ float Wc[64][128];
    const int t  = threadIdx.x;
    const int tx = t & 15;
    const int ty = t >> 4;
    const int row0 = blockIdx.x * 64;

    float acc[4][8];
#pragma unroll
    for (int i = 0; i < 4; ++i)
#pragma unroll
        for (int j = 0; j < 8; ++j) acc[i][j] = 0.0f;

    for (int c = 0; c < 2; ++c) {
        if (c) __syncthreads();
        {
            const int k4 = (t & 15) * 4;
            const int rbase = t >> 4;
#pragma unroll
            for (int p = 0; p < 4; ++p) {
                const int rr = rbase + p * 16;
                const int grow = row0 + rr;
                float4 v = make_float4(0.f, 0.f, 0.f, 0.f);
                if (grow < M)
                    v = *reinterpret_cast<const float4*>(&feat[(size_t)grow * 128 + c * 64 + k4]);
                *reinterpret_cast<float4*>(&As[rr][k4]) = v;
            }
        }
        {
#pragma unroll
            for (int p = 0; p < 8; ++p) {
                const int idx = (p * 256 + t) * 4;
                const int kk = idx >> 7;
                const int j = idx & 127;
                *reinterpret_cast<float4*>(&Wc[kk][j]) =
                    *reinterpret_cast<const float4*>(&weight[(c * 64 + kk) * 128 + j]);
            }
        }
        __syncthreads();

#pragma unroll 8
        for (int k = 0; k < 64; ++k) {
            float a[4];
#pragma unroll
            for (int i = 0; i < 4; ++i) a[i] = As[ty * 4 + i][k];
            const float4 b0 = *reinterpret_cast<const float4*>(&Wc[k][tx * 8 + 0]);
            const float4 b1 = *reinterpret_cast<const float4*>(&Wc[k][tx * 8 + 4]);
            const float b[8] = {b0.x, b0.y, b0.z, b0.w, b1.x, b1.y, b1.z, b1.w};
#pragma unroll
            for (int i = 0; i < 4; ++i)
#pragma unroll
                for (int j = 0; j < 8; ++j)
                    acc[i][j] = fmaf(a[i], b[j], acc[i][j]);
        }
    }

#pragma unroll
    for (int i = 0; i < 4; ++i) {
        const int grow = row0 + ty * 4 + i;
        if (grow < M) {
            union { ushort u16[8]; uint4 v; } pk;
#pragma unroll
            for (int j = 0; j < 8; ++j) {
                const uint u = __float_as_uint(acc[i][j]);
                pk.u16[j] = (ushort)((u + 0x7fffu + ((u >> 16) & 1u)) >> 16);  // RNE to bf16
            }
            *reinterpret_cast<uint4*>(&h[(size_t)grow * 128 + tx * 8]) = pk.v;
        }
    }
}

// ---------- Phase B: out[n] = (sum h[s]) * rsqrt(max(deg,1)) + bias ----------
// Quarter-wave layout: 16 lanes x uint4 (8 bf16) per row => 4 edges per wave
// instruction, 16 edges in flight; two shfl_xor merges across quarters.
__global__ __launch_bounds__(256) void aggregate_h(const ushort* __restrict__ h,
                                                   const int* __restrict__ csr,
                                                   const int* __restrict__ off,
                                                   const int* __restrict__ deg,
                                                   const float* __restrict__ bias,
                                                   float* __restrict__ out, int N) {
    const int node = (blockIdx.x * blockDim.x + threadIdx.x) >> 6;
    if (node >= N) return;
    const int lane = threadIdx.x & 63;
    const int q   = lane >> 4;    // quarter 0..3 -> edge slot
    const int sub = lane & 15;    // column group: cols sub*8 .. sub*8+7
    const int start = off[node];
    const int cnt   = deg[node];
    const int end   = start + cnt;

    float acc[8];
#pragma unroll
    for (int k = 0; k < 8; ++k) acc[k] = 0.0f;

#define UNPACK_ADD(rr)                                             \
    do {                                                           \
        acc[0] += __uint_as_float(((rr).x & 0xffffu) << 16);       \
        acc[1] += __uint_as_float((rr).x & 0xffff0000u);           \
        acc[2] += __uint_as_float(((rr).y & 0xffffu) << 16);       \
        acc[3] += __uint_as_float((rr).y & 0xffff0000u);           \
        acc[4] += __uint_as_float(((rr).z & 0xffffu) << 16);       \
        acc[5] += __uint_as_float((rr).z & 0xffff0000u);           \
        acc[6] += __uint_as_float(((rr).w & 0xffffu) << 16);       \
        acc[7] += __uint_as_float((rr).w & 0xffff0000u);           \
    } while (0)

    int j = start;
    for (; j + 15 < end; j += 16) {
        int s[4];
#pragma unroll
        for (int k = 0; k < 4; ++k) s[k] = csr[j + q + 4 * k];
        uint4 r[4];
#pragma unroll
        for (int k = 0; k < 4; ++k)
            r[k] = *reinterpret_cast<const uint4*>(h + (size_t)s[k] * 128 + sub * 8);
#pragma unroll
        for (int k = 0; k < 4; ++k) UNPACK_ADD(r[k]);
    }
    for (; j + 3 < end; j += 4) {
        const int s = csr[j + q];
        const uint4 rr = *reinterpret_cast<const uint4*>(h + (size_t)s * 128 + sub * 8);
        UNPACK_ADD(rr);
    }
    const int rem = end - j;
    if (q < rem) {
        const int s = csr[j + q];
        const uint4 rr = *reinterpret_cast<const uint4*>(h + (size_t)s * 128 + sub * 8);
        UNPACK_ADD(rr);
    }
#undef UNPACK_ADD

#pragma unroll
    for (int k = 0; k < 8; ++k) {
        acc[k] += __shfl_xor(acc[k], 16, 64);
        acc[k] += __shfl_xor(acc[k], 32, 64);
    }

    if (lane < 16) {
        const float nm = rsqrtf(fmaxf((float)cnt, 1.0f));
        const float4 b0 = *reinterpret_cast<const float4*>(bias + sub * 8 + 0);
        const float4 b1 = *reinterpret_cast<const float4*>(bias + sub * 8 + 4);
        float4 o0, o1;
        o0.x = fmaf(acc[0], nm, b0.x);
        o0.y = fmaf(acc[1], nm, b0.y);
        o0.z = fmaf(acc[2], nm, b0.z);
        o0.w = fmaf(acc[3], nm, b0.w);
        o1.x = fmaf(acc[4], nm, b1.x);
        o1.y = fmaf(acc[5], nm, b1.y);
        o1.z = fmaf(acc[6], nm, b1.z);
        o1.w = fmaf(acc[7], nm, b1.w);
        *reinterpret_cast<float4*>(out + (size_t)node * 128 + sub * 8 + 0) = o0;
        *reinterpret_cast<float4*>(out + (size_t)node * 128 + sub * 8 + 4) = o1;
    }
}

// ---------- Fallback path (ws too small) ----------
__global__ void hist_simple(const int* __restrict__ dst, int* __restrict__ deg, int nE) {
    int e = blockIdx.x * blockDim.x + threadIdx.x;
    if (e < nE) atomicAdd(&deg[dst[e]], 1);
}
__global__ void bucket_simple(const int* __restrict__ src, const int* __restrict__ dst,
                              int* __restrict__ cur, int* __restrict__ csr, int nE) {
    int e = blockIdx.x * blockDim.x + threadIdx.x;
    if (e < nE) {
        int pos = atomicAdd(&cur[dst[e]], 1);
        csr[pos] = src[e];
    }
}
__global__ __launch_bounds__(256) void scan_chunks(const int* __restrict__ deg,
                                                   int* __restrict__ off,
                                                   int* __restrict__ partials, int N) {
    __shared__ int sums[256];
    const int b = blockIdx.x, t = threadIdx.x;
    const int base = b * CHUNK + t * 4;
    int v[4];
#pragma unroll
    for (int i = 0; i < 4; ++i) v[i] = (base + i < N) ? deg[base + i] : 0;
    const int s = v[0] + v[1] + v[2] + v[3];
    sums[t] = s;
    __syncthreads();
    for (int d = 1; d < 256; d <<= 1) {
        int x = (t >= d) ? sums[t - d] : 0;
        __syncthreads();
        sums[t] += x;
        __syncthreads();
    }
    const int excl = sums[t] - s;
    if (t == 255) partials[b] = sums[255];
    int run = excl;
#pragma unroll
    for (int i = 0; i < 4; ++i) {
        if (base + i < N) off[base + i] = run;
        run += v[i];
    }
}
__global__ __launch_bounds__(256) void scan_partials(int* partials, int P) {
    __shared__ int buf[256];
    const int t = threadIdx.x;
    if (P <= 256) {
        const int v = (t < P) ? partials[t] : 0;
        buf[t] = v;
        __syncthreads();
        for (int d = 1; d < 256; d <<= 1) {
            int x = (t >= d) ? buf[t - d] : 0;
            __syncthreads();
            buf[t] += x;
            __syncthreads();
        }
        if (t < P) partials[t] = buf[t] - v;
    } else if (t == 0) {
        int acc = 0;
        for (int i = 0; i < P; ++i) { int v = partials[i]; partials[i] = acc; acc += v; }
    }
}
__global__ void add_base(int* __restrict__ off, int* __restrict__ cur,
                         const int* __restrict__ partials, int N) {
    int i = blockIdx.x * blockDim.x + threadIdx.x;
    if (i < N) {
        int o = off[i] + partials[i >> 10];
        off[i] = o;
        cur[i] = o;
    }
}
__global__ __launch_bounds__(256) void aggregate_f32(const float* __restrict__ feat,
                                                     const int* __restrict__ csr,
                                                     const int* __restrict__ off,
                                                     const int* __restrict__ deg,
                                                     float* __restrict__ out, int N) {
    const int node = (blockIdx.x * blockDim.x + threadIdx.x) >> 6;
    if (node >= N) return;
    const int lane = threadIdx.x & 63;
    const int start = off[node];
    const int end   = start + deg[node];
    const float2* feat2 = reinterpret_cast<const float2*>(feat);
    float ax = 0.0f, ay = 0.0f;
    for (int j = start; j < end; ++j) {
        const float2 v = feat2[(size_t)csr[j] * 64 + lane];
        ax += v.x;
        ay += v.y;
    }
    reinterpret_cast<float2*>(out)[(size_t)node * 64 + lane] = make_float2(ax, ay);
}
__global__ __launch_bounds__(256) void gemm_norm(const float* agg,
                                                 const float* __restrict__ weight,
                                                 const float* __restrict__ bias,
                                                 const int* __restrict__ deg,
                                                 float* out, int M) {
    __shared__ float As[64][68];
    __shared__ float Wc[64][128];
    const int t  = threadIdx.x;
    const int tx = t & 15;
    const int ty = t >> 4;
    const int row0 = blockIdx.x * 64;
    float acc[4][8];
#pragma unroll
    for (int i = 0; i < 4; ++i)
#pragma unroll
        for (int j = 0; j < 8; ++j) acc[i][j] = 0.0f;
    for (int c = 0; c < 2; ++c) {
        if (c) __syncthreads();
        {
            const int k4 = (t & 15) * 4;
            const int rbase = t >> 4;
#pragma unroll
            for (int p = 0; p < 4; ++p) {
                const int rr = rbase + p * 16;
                const int grow = row0 + rr;
                float4 v = make_float4(0.f, 0.f, 0.f, 0.f);
                if (grow < M)
                    v = *reinterpret_cast<const float4*>(&agg[(size_t)grow * 128 + c * 64 + k4]);
                *reinterpret_cast<float4*>(&As[rr][k4]) = v;
            }
        }
        {
#pragma unroll
            for (int p = 0; p < 8; ++p) {
                const int idx = (p * 256 + t) * 4;
                const int kk = idx >> 7;
                const int j = idx & 127;
                *reinterpret_cast<float4*>(&Wc[kk][j]) =
                    *reinterpret_cast<const float4*>(&weight[(c * 64 + kk) * 128 + j]);
            }
        }
        __syncthreads();
#pragma unroll 8
        for (int k = 0; k < 64; ++k) {
            float a[4];
#pragma unroll
            for (int i = 0; i < 4; ++i) a[i] = As[ty * 4 + i][k];
            const float4 b0 = *reinterpret_cast<const float4*>(&Wc[k][tx * 8 + 0]);
            const float4 b1 = *reinterpret_cast<const float4*>(&Wc[k][tx * 8 + 4]);
            const float b[8] = {b0.x, b0.y, b0.z, b0.w, b1.x, b1.y, b1.z, b1.w};
#pragma unroll
            for (int i = 0; i < 4; ++i)
#pragma unroll
                for (int j = 0; j < 8; ++j)
                    acc[i][j] = fmaf(a[i], b[j], acc[i][j]);
        }
    }
    float bcol[8];
#pragma unroll
    for (int j = 0; j < 8; ++j) bcol[j] = bias[tx * 8 + j];
#pragma unroll
    for (int i = 0; i < 4; ++i) {
        const int grow = row0 + ty * 4 + i;
        if (grow < M) {
            const float nm = rsqrtf(fmaxf((float)deg[grow], 1.0f));
            float4 o0, o1;
            o0.x = fmaf(acc[i][0], nm, bcol[0]);
            o0.y = fmaf(acc[i][1], nm, bcol[1]);
            o0.z = fmaf(acc[i][2], nm, bcol[2]);
            o0.w = fmaf(acc[i][3], nm, bcol[3]);
            o1.x = fmaf(acc[i][4], nm, bcol[4]);
            o1.y = fmaf(acc[i][5], nm, bcol[5]);
            o1.z = fmaf(acc[i][6], nm, bcol[6]);
            o1.w = fmaf(acc[i][7], nm, bcol[7]);
            *reinterpret_cast<float4*>(&out[(size_t)grow * 128 + tx * 8 + 0]) = o0;
            *reinterpret_cast<float4*>(&out[(size_t)grow * 128 + tx * 8 + 4]) = o1;
        }
    }
}

extern "C" void kernel_launch(void* const* d_in, const int* in_sizes, int n_in,
                              void* d_out, int out_size, void* d_ws, size_t ws_size,
                              hipStream_t stream) {
    const float* feat   = (const float*)d_in[0];
    const int*   src    = (const int*)d_in[1];
    const int*   dst    = (const int*)d_in[2];
    const float* weight = (const float*)d_in[3];
    const float* bias   = (const float*)d_in[4];
    float* out = (float*)d_out;

    const int nE = in_sizes[1];
    const int M  = in_sizes[0] / 128;
    const int P  = (M + CHUNK - 1) / CHUNK;

    // ws layout (ints): deg[M] | off[M] | cur[M] | partials[256] | gcur[RR] | csr[nE] | staging∪h
    int* degi     = (int*)d_ws;
    int* off      = degi + M;
    int* cur      = off + M;
    int* partials = cur + M;
    int* gcur     = partials + 256;
    int* csr      = gcur + RR;
    const size_t csr_end   = ((size_t)3 * M + 256 + RR + (size_t)nE) * sizeof(int);
    const size_t stage_off = (csr_end + 15) & ~(size_t)15;
    const int cap = (((nE + RR - 1) / RR + 8192) + 3) & ~3;   // per-range staging cap (int2)
    int2* staging = (int2*)((char*)d_ws + stage_off);
    ushort* h     = (ushort*)staging;                          // h aliases staging
    const size_t stage_bytes = (size_t)RR * cap * sizeof(int2);
    const size_t h_bytes     = (size_t)M * 128 * sizeof(ushort);
    const size_t need_big = stage_off + (stage_bytes > h_bytes ? stage_bytes : h_bytes);

    if (ws_size >= need_big) {
        hipMemsetAsync(gcur, 0, RR * sizeof(int), stream);
        partition64<<<1024, 256, 0, stream>>>(src, dst, gcur, staging, cap, nE, M);
        range_build<<<RR, 1024, 0, stream>>>(staging, gcur, degi, off, csr, cap, M);
        gemm_h<<<(M + 63) / 64, 256, 0, stream>>>(feat, weight, h, M);  // overwrites staging
        aggregate_h<<<(M + 3) / 4, 256, 0, stream>>>(h, csr, off, degi, bias, out, M);
    } else {
        hipMemsetAsync(degi, 0, (size_t)M * sizeof(int), stream);
        hist_simple<<<(nE + 255) / 256, 256, 0, stream>>>(dst, degi, nE);
        scan_chunks<<<P, 256, 0, stream>>>(degi, off, partials, M);
        scan_partials<<<1, 256, 0, stream>>>(partials, P);
        add_base<<<(M + 255) / 256, 256, 0, stream>>>(off, cur, partials, M);
        bucket_simple<<<(nE + 255) / 256, 256, 0, stream>>>(src, dst, cur, csr, nE);
        aggregate_f32<<<(M + 3) / 4, 256, 0, stream>>>(feat, csr, off, degi, out, M);
        gemm_norm<<<(M + 63) / 64, 256, 0, stream>>>(out, weight, bias, degi, out, M);
    }
}

// Round 8
// 248.707 us; speedup vs baseline: 1.5354x; 1.0818x over previous
//
#include <hip/hip_runtime.h>
#include <hip/hip_bf16.h>

#define CHUNK 1024
#define RR 64          // dst ranges
#define DEPTH 64       // LDS bin depth (pairs) per range per round
#define WMAX 1600      // max nodes per range (ceil(100000/64)=1563)
typedef unsigned int uint;
typedef unsigned short ushort;

typedef __bf16 bf16x8 __attribute__((ext_vector_type(8)));
typedef float  f32x4  __attribute__((ext_vector_type(4)));

__device__ __forceinline__ ushort f2bf(float f) {
    const uint u = __float_as_uint(f);
    return (ushort)((u + 0x7fffu + ((u >> 16) & 1u)) >> 16);  // RNE
}

// ---------- Phase 0: single-pass partition into RR dst-ranges ----------
__global__ __launch_bounds__(256) void partition64(const int* __restrict__ src,
                                                   const int* __restrict__ dst,
                                                   int* __restrict__ gcur,
                                                   int2* __restrict__ staging,
                                                   int cap, int nE, int N) {
    __shared__ int2 bins[RR][DEPTH];
    __shared__ int cnt[RR];
    __shared__ int res[RR];
    const int t  = threadIdx.x;
    const int nb = gridDim.x;
    const int rounds = (nE + nb * 1024 - 1) / (nb * 1024);

    for (int rd = 0; rd < rounds; ++rd) {
        if (t < RR) cnt[t] = 0;
        __syncthreads();

        const int e4 = (rd * nb + blockIdx.x) * 1024 + t * 4;
        int s[4], d[4];
        int nv = 0;
        if (e4 + 3 < nE) {
            const int4 s4 = *reinterpret_cast<const int4*>(src + e4);
            const int4 d4 = *reinterpret_cast<const int4*>(dst + e4);
            s[0] = s4.x; s[1] = s4.y; s[2] = s4.z; s[3] = s4.w;
            d[0] = d4.x; d[1] = d4.y; d[2] = d4.z; d[3] = d4.w;
            nv = 4;
        } else {
            for (int e = e4; e < nE; ++e) { s[nv] = src[e]; d[nv] = dst[e]; ++nv; }
        }
#pragma unroll
        for (int i = 0; i < 4; ++i) {
            if (i < nv) {
                const int r = (int)(((long long)d[i] * RR) / N);
                const int pos = atomicAdd(&cnt[r], 1);
                if (pos < DEPTH) {
                    bins[r][pos] = make_int2(s[i], d[i]);
                } else {
                    const int gp = atomicAdd(&gcur[r], 1);
                    staging[(size_t)r * cap + gp] = make_int2(s[i], d[i]);
                }
            }
        }
        __syncthreads();
        if (t < RR) {
            int c = cnt[t];
            c = c < DEPTH ? c : DEPTH;
            cnt[t] = c;
            res[t] = (c > 0) ? atomicAdd(&gcur[t], c) : 0;
        }
        __syncthreads();
        {
            const int g = t >> 2;
            const int l = t & 3;
            const int c = cnt[g];
            const int b = res[g];
            for (int i = l; i < c; i += 4)
                staging[(size_t)g * cap + b + i] = bins[g][i];
        }
        __syncthreads();
    }
}

// ---------- Phase 1: per-range CSR build entirely in LDS ----------
__global__ __launch_bounds__(1024) void range_build(const int2* __restrict__ staging,
                                                    const int* __restrict__ gcur,
                                                    int* __restrict__ deg,
                                                    int* __restrict__ off,
                                                    int* __restrict__ csr,
                                                    int cap, int N) {
    __shared__ int hist[WMAX];
    __shared__ int sbuf[1024];
    __shared__ int sbase;
    const int r = blockIdx.x;
    const int t = threadIdx.x;
    const int lo = (int)(((long long)r * N + RR - 1) / RR);
    const int hi = (int)(((long long)(r + 1) * N + RR - 1) / RR);
    const int W  = hi - lo;
    const int cnt = gcur[r];

    if (t < RR) sbuf[t] = gcur[t];
    for (int i = t; i < W; i += 1024) hist[i] = 0;
    __syncthreads();
    if (t == 0) {
        int b = 0;
        for (int i = 0; i < r; ++i) b += sbuf[i];
        sbase = b;
    }
    const int2* ep = staging + (size_t)r * cap;
    for (int i = t; i < cnt; i += 1024) {
        const int2 p = ep[i];
        atomicAdd(&hist[p.y - lo], 1);
    }
    __syncthreads();
    const int base = sbase;

    const int i0 = t * 2, i1 = t * 2 + 1;
    const int a = (i0 < W) ? hist[i0] : 0;
    const int b = (i1 < W) ? hist[i1] : 0;
    if (i0 < W) deg[lo + i0] = a;
    if (i1 < W) deg[lo + i1] = b;
    const int tsum = a + b;
    sbuf[t] = tsum;
    __syncthreads();
    for (int dd = 1; dd < 1024; dd <<= 1) {
        const int x = (t >= dd) ? sbuf[t - dd] : 0;
        __syncthreads();
        sbuf[t] += x;
        __syncthreads();
    }
    const int excl = sbuf[t] - tsum;
    if (i0 < W) { off[lo + i0] = base + excl;     hist[i0] = base + excl; }
    if (i1 < W) { off[lo + i1] = base + excl + a; hist[i1] = base + excl + a; }
    __syncthreads();

    for (int i = t; i < cnt; i += 1024) {
        const int2 p = ep[i];
        const int pos = atomicAdd(&hist[p.y - lo], 1);
        csr[pos] = p.x;
    }
}

// ---------- W prep: wt[n][k] = bf16(W[k][n])  (B-fragment friendly) ----------
__global__ __launch_bounds__(256) void prep_w(const float* __restrict__ w,
                                              ushort* __restrict__ wt) {
    const int idx = blockIdx.x * 256 + threadIdx.x;  // 0..16383
    const int k = idx >> 7;
    const int n = idx & 127;
    wt[n * 128 + k] = f2bf(w[k * 128 + n]);
}

// ---------- Phase A: h = feat @ W via bf16 MFMA, output bf16 ----------
// Block: 4 waves, 64 rows x 128 cols. B-frags (whole W^T) register-resident.
// A staged bf16 in LDS, pad 136 => bank-balanced ds_read_b128 fragments.
#define APITCH 136
__global__ __launch_bounds__(256, 2) void gemm_mfma(const float* __restrict__ feat,
                                                    const ushort* __restrict__ wt,
                                                    ushort* __restrict__ h, int M) {
    __shared__ ushort A_lds[64 * APITCH];
    const int t    = threadIdx.x;
    const int wave = t >> 6;
    const int lane = t & 63;
    const int quad = lane >> 4;
    const int nn   = lane & 15;
    const int row0 = blockIdx.x * 64;

    // B fragments: b[ct][kc], lane holds Wt[ct*16+nn][kc*32+quad*8 .. +7]
    union UB { uint4 u; bf16x8 b; };
    UB bfrag[8][4];
#pragma unroll
    for (int ct = 0; ct < 8; ++ct)
#pragma unroll
        for (int kc = 0; kc < 4; ++kc)
            bfrag[ct][kc].u = *reinterpret_cast<const uint4*>(
                wt + (ct * 16 + nn) * 128 + kc * 32 + quad * 8);

    // Stage feat rows -> bf16 LDS tile [64][APITCH]
#pragma unroll
    for (int p = 0; p < 8; ++p) {
        const int idx = p * 256 + t;          // 0..2047 float4-granules
        const int row = idx >> 5;
        const int c4  = (idx & 31) * 4;
        const int grow = row0 + row;
        float4 v = make_float4(0.f, 0.f, 0.f, 0.f);
        if (grow < M)
            v = *reinterpret_cast<const float4*>(&feat[(size_t)grow * 128 + c4]);
        const uint2 pk = make_uint2((uint)f2bf(v.x) | ((uint)f2bf(v.y) << 16),
                                    (uint)f2bf(v.z) | ((uint)f2bf(v.w) << 16));
        *reinterpret_cast<uint2*>(&A_lds[row * APITCH + c4]) = pk;
    }
    __syncthreads();

    // A fragments for this wave's 16 rows: lane row = nn, k = kc*32+quad*8
    union UA { uint4 u; bf16x8 b; };
    UA afrag[4];
#pragma unroll
    for (int kc = 0; kc < 4; ++kc)
        afrag[kc].u = *reinterpret_cast<const uint4*>(
            &A_lds[(wave * 16 + nn) * APITCH + kc * 32 + quad * 8]);

    f32x4 acc[8];
#pragma unroll
    for (int ct = 0; ct < 8; ++ct) {
        acc[ct] = (f32x4){0.f, 0.f, 0.f, 0.f};
#pragma unroll
        for (int kc = 0; kc < 4; ++kc)
            acc[ct] = __builtin_amdgcn_mfma_f32_16x16x32_bf16(
                afrag[kc].b, bfrag[ct][kc].b, acc[ct], 0, 0, 0);
    }
    __syncthreads();   // all A reads done; reuse LDS for C

    // C/D layout: col = ct*16+nn, row_local = wave*16 + quad*4 + reg
#pragma unroll
    for (int ct = 0; ct < 8; ++ct) {
#pragma unroll
        for (int reg = 0; reg < 4; ++reg) {
            const int rl = wave * 16 + quad * 4 + reg;
            A_lds[rl * APITCH + ct * 16 + nn] = f2bf(acc[ct][reg]);
        }
    }
    __syncthreads();

    // Coalesced store: 4 x uint4 per thread
#pragma unroll
    for (int p = 0; p < 4; ++p) {
        const int idx = p * 256 + t;          // 0..1023 uint4-granules
        const int row = idx >> 4;
        const int c16 = idx & 15;
        const int grow = row0 + row;
        if (grow < M) {
            const uint4 v = *reinterpret_cast<const uint4*>(&A_lds[row * APITCH + c16 * 8]);
            *reinterpret_cast<uint4*>(&h[(size_t)grow * 128 + c16 * 8]) = v;
        }
    }
}

// ---------- Phase B: out[n] = (sum h[s]) * rsqrt(max(deg,1)) + bias ----------
__global__ __launch_bounds__(256) void aggregate_h(const ushort* __restrict__ h,
                                                   const int* __restrict__ csr,
                                                   const int* __restrict__ off,
                                                   const int* __restrict__ deg,
                                                   const float* __restrict__ bias,
                                                   float* __restrict__ out, int N) {
    const int node = (blockIdx.x * blockDim.x + threadIdx.x) >> 6;
    if (node >= N) return;
    const int lane = threadIdx.x & 63;
    const int q   = lane >> 4;
    const int sub = lane & 15;
    const int start = off[node];
    const int cnt   = deg[node];
    const int end   = start + cnt;

    float acc[8];
#pragma unroll
    for (int k = 0; k < 8; ++k) acc[k] = 0.0f;

#define UNPACK_ADD(rr)                                             \
    do {                                                           \
        acc[0] += __uint_as_float(((rr).x & 0xffffu) << 16);       \
        acc[1] += __uint_as_float((rr).x & 0xffff0000u);           \
        acc[2] += __uint_as_float(((rr).y & 0xffffu) << 16);       \
        acc[3] += __uint_as_float((rr).y & 0xffff0000u);           \
        acc[4] += __uint_as_float(((rr).z & 0xffffu) << 16);       \
        acc[5] += __uint_as_float((rr).z & 0xffff0000u);           \
        acc[6] += __uint_as_float(((rr).w & 0xffffu) << 16);       \
        acc[7] += __uint_as_float((rr).w & 0xffff0000u);           \
    } while (0)

    int j = start;
    for (; j + 15 < end; j += 16) {
        int s[4];
#pragma unroll
        for (int k = 0; k < 4; ++k) s[k] = csr[j + q + 4 * k];
        uint4 r[4];
#pragma unroll
        for (int k = 0; k < 4; ++k)
            r[k] = *reinterpret_cast<const uint4*>(h + (size_t)s[k] * 128 + sub * 8);
#pragma unroll
        for (int k = 0; k < 4; ++k) UNPACK_ADD(r[k]);
    }
    for (; j + 3 < end; j += 4) {
        const int s = csr[j + q];
        const uint4 rr = *reinterpret_cast<const uint4*>(h + (size_t)s * 128 + sub * 8);
        UNPACK_ADD(rr);
    }
    const int rem = end - j;
    if (q < rem) {
        const int s = csr[j + q];
        const uint4 rr = *reinterpret_cast<const uint4*>(h + (size_t)s * 128 + sub * 8);
        UNPACK_ADD(rr);
    }
#undef UNPACK_ADD

#pragma unroll
    for (int k = 0; k < 8; ++k) {
        acc[k] += __shfl_xor(acc[k], 16, 64);
        acc[k] += __shfl_xor(acc[k], 32, 64);
    }

    if (lane < 16) {
        const float nm = rsqrtf(fmaxf((float)cnt, 1.0f));
        const float4 b0 = *reinterpret_cast<const float4*>(bias + sub * 8 + 0);
        const float4 b1 = *reinterpret_cast<const float4*>(bias + sub * 8 + 4);
        float4 o0, o1;
        o0.x = fmaf(acc[0], nm, b0.x);
        o0.y = fmaf(acc[1], nm, b0.y);
        o0.z = fmaf(acc[2], nm, b0.z);
        o0.w = fmaf(acc[3], nm, b0.w);
        o1.x = fmaf(acc[4], nm, b1.x);
        o1.y = fmaf(acc[5], nm, b1.y);
        o1.z = fmaf(acc[6], nm, b1.z);
        o1.w = fmaf(acc[7], nm, b1.w);
        *reinterpret_cast<float4*>(out + (size_t)node * 128 + sub * 8 + 0) = o0;
        *reinterpret_cast<float4*>(out + (size_t)node * 128 + sub * 8 + 4) = o1;
    }
}

// ---------- Fallback path (ws too small) ----------
__global__ void hist_simple(const int* __restrict__ dst, int* __restrict__ deg, int nE) {
    int e = blockIdx.x * blockDim.x + threadIdx.x;
    if (e < nE) atomicAdd(&deg[dst[e]], 1);
}
__global__ void bucket_simple(const int* __restrict__ src, const int* __restrict__ dst,
                              int* __restrict__ cur, int* __restrict__ csr, int nE) {
    int e = blockIdx.x * blockDim.x + threadIdx.x;
    if (e < nE) {
        int pos = atomicAdd(&cur[dst[e]], 1);
        csr[pos] = src[e];
    }
}
__global__ __launch_bounds__(256) void scan_chunks(const int* __restrict__ deg,
                                                   int* __restrict__ off,
                                                   int* __restrict__ partials, int N) {
    __shared__ int sums[256];
    const int b = blockIdx.x, t = threadIdx.x;
    const int base = b * CHUNK + t * 4;
    int v[4];
#pragma unroll
    for (int i = 0; i < 4; ++i) v[i] = (base + i < N) ? deg[base + i] : 0;
    const int s = v[0] + v[1] + v[2] + v[3];
    sums[t] = s;
    __syncthreads();
    for (int d = 1; d < 256; d <<= 1) {
        int x = (t >= d) ? sums[t - d] : 0;
        __syncthreads();
        sums[t] += x;
        __syncthreads();
    }
    const int excl = sums[t] - s;
    if (t == 255) partials[b] = sums[255];
    int run = excl;
#pragma unroll
    for (int i = 0; i < 4; ++i) {
        if (base + i < N) off[base + i] = run;
        run += v[i];
    }
}
__global__ __launch_bounds__(256) void scan_partials(int* partials, int P) {
    __shared__ int buf[256];
    const int t = threadIdx.x;
    if (P <= 256) {
        const int v = (t < P) ? partials[t] : 0;
        buf[t] = v;
        __syncthreads();
        for (int d = 1; d < 256; d <<= 1) {
            int x = (t >= d) ? buf[t - d] : 0;
            __syncthreads();
            buf[t] += x;
            __syncthreads();
        }
        if (t < P) partials[t] = buf[t] - v;
    } else if (t == 0) {
        int acc = 0;
        for (int i = 0; i < P; ++i) { int v = partials[i]; partials[i] = acc; acc += v; }
    }
}
__global__ void add_base(int* __restrict__ off, int* __restrict__ cur,
                         const int* __restrict__ partials, int N) {
    int i = blockIdx.x * blockDim.x + threadIdx.x;
    if (i < N) {
        int o = off[i] + partials[i >> 10];
        off[i] = o;
        cur[i] = o;
    }
}
__global__ __launch_bounds__(256) void aggregate_f32(const float* __restrict__ feat,
                                                     const int* __restrict__ csr,
                                                     const int* __restrict__ off,
                                                     const int* __restrict__ deg,
                                                     float* __restrict__ out, int N) {
    const int node = (blockIdx.x * blockDim.x + threadIdx.x) >> 6;
    if (node >= N) return;
    const int lane = threadIdx.x & 63;
    const int start = off[node];
    const int end   = start + deg[node];
    const float2* feat2 = reinterpret_cast<const float2*>(feat);
    float ax = 0.0f, ay = 0.0f;
    for (int j = start; j < end; ++j) {
        const float2 v = feat2[(size_t)csr[j] * 64 + lane];
        ax += v.x;
        ay += v.y;
    }
    reinterpret_cast<float2*>(out)[(size_t)node * 64 + lane] = make_float2(ax, ay);
}
__global__ __launch_bounds__(256) void gemm_norm(const float* agg,
                                                 const float* __restrict__ weight,
                                                 const float* __restrict__ bias,
                                                 const int* __restrict__ deg,
                                                 float* out, int M) {
    __shared__ float As[64][68];
    __shared__ float Wc[64][128];
    const int t  = threadIdx.x;
    const int tx = t & 15;
    const int ty = t >> 4;
    const int row0 = blockIdx.x * 64;
    float acc[4][8];
#pragma unroll
    for (int i = 0; i < 4; ++i)
#pragma unroll
        for (int j = 0; j < 8; ++j) acc[i][j] = 0.0f;
    for (int c = 0; c < 2; ++c) {
        if (c) __syncthreads();
        {
            const int k4 = (t & 15) * 4;
            const int rbase = t >> 4;
#pragma unroll
            for (int p = 0; p < 4; ++p) {
                const int rr = rbase + p * 16;
                const int grow = row0 + rr;
                float4 v = make_float4(0.f, 0.f, 0.f, 0.f);
                if (grow < M)
                    v = *reinterpret_cast<const float4*>(&agg[(size_t)grow * 128 + c * 64 + k4]);
                *reinterpret_cast<float4*>(&As[rr][k4]) = v;
            }
        }
        {
#pragma unroll
            for (int p = 0; p < 8; ++p) {
                const int idx = (p * 256 + t) * 4;
                const int kk = idx >> 7;
                const int j = idx & 127;
                *reinterpret_cast<float4*>(&Wc[kk][j]) =
                    *reinterpret_cast<const float4*>(&weight[(c * 64 + kk) * 128 + j]);
            }
        }
        __syncthreads();
#pragma unroll 8
        for (int k = 0; k < 64; ++k) {
            float a[4];
#pragma unroll
            for (int i = 0; i < 4; ++i) a[i] = As[ty * 4 + i][k];
            const float4 b0 = *reinterpret_cast<const float4*>(&Wc[k][tx * 8 + 0]);
            const float4 b1 = *reinterpret_cast<const float4*>(&Wc[k][tx * 8 + 4]);
            const float b[8] = {b0.x, b0.y, b0.z, b0.w, b1.x, b1.y, b1.z, b1.w};
#pragma unroll
            for (int i = 0; i < 4; ++i)
#pragma unroll
                for (int j = 0; j < 8; ++j)
                    acc[i][j] = fmaf(a[i], b[j], acc[i][j]);
        }
    }
    float bcol[8];
#pragma unroll
    for (int j = 0; j < 8; ++j) bcol[j] = bias[tx * 8 + j];
#pragma unroll
    for (int i = 0; i < 4; ++i) {
        const int grow = row0 + ty * 4 + i;
        if (grow < M) {
            const float nm = rsqrtf(fmaxf((float)deg[grow], 1.0f));
            float4 o0, o1;
            o0.x = fmaf(acc[i][0], nm, bcol[0]);
            o0.y = fmaf(acc[i][1], nm, bcol[1]);
            o0.z = fmaf(acc[i][2], nm, bcol[2]);
            o0.w = fmaf(acc[i][3], nm, bcol[3]);
            o1.x = fmaf(acc[i][4], nm, bcol[4]);
            o1.y = fmaf(acc[i][5], nm, bcol[5]);
            o1.z = fmaf(acc[i][6], nm, bcol[6]);
            o1.w = fmaf(acc[i][7], nm, bcol[7]);
            *reinterpret_cast<float4*>(&out[(size_t)grow * 128 + tx * 8 + 0]) = o0;
            *reinterpret_cast<float4*>(&out[(size_t)grow * 128 + tx * 8 + 4]) = o1;
        }
    }
}

extern "C" void kernel_launch(void* const* d_in, const int* in_sizes, int n_in,
                              void* d_out, int out_size, void* d_ws, size_t ws_size,
                              hipStream_t stream) {
    const float* feat   = (const float*)d_in[0];
    const int*   src    = (const int*)d_in[1];
    const int*   dst    = (const int*)d_in[2];
    const float* weight = (const float*)d_in[3];
    const float* bias   = (const float*)d_in[4];
    float* out = (float*)d_out;

    const int nE = in_sizes[1];
    const int M  = in_sizes[0] / 128;
    const int P  = (M + CHUNK - 1) / CHUNK;

    // ws: deg[M]|off[M]|cur[M]|partials[256]|gcur[RR]|csr[nE]|wt[16384]|staging∪h
    int* degi     = (int*)d_ws;
    int* off      = degi + M;
    int* cur      = off + M;
    int* partials = cur + M;
    int* gcur     = partials + 256;
    int* csr      = gcur + RR;
    ushort* wt    = (ushort*)(csr + nE);
    const size_t wt_end    = ((size_t)3 * M + 256 + RR + (size_t)nE) * sizeof(int) + 32768;
    const size_t stage_off = (wt_end + 15) & ~(size_t)15;
    const int cap = (((nE + RR - 1) / RR + 8192) + 3) & ~3;
    int2* staging = (int2*)((char*)d_ws + stage_off);
    ushort* h     = (ushort*)staging;                          // h aliases staging
    const size_t stage_bytes = (size_t)RR * cap * sizeof(int2);
    const size_t h_bytes     = (size_t)M * 128 * sizeof(ushort);
    const size_t need_big = stage_off + (stage_bytes > h_bytes ? stage_bytes : h_bytes);

    if (ws_size >= need_big) {
        hipMemsetAsync(gcur, 0, RR * sizeof(int), stream);
        prep_w<<<64, 256, 0, stream>>>(weight, wt);
        partition64<<<1024, 256, 0, stream>>>(src, dst, gcur, staging, cap, nE, M);
        range_build<<<RR, 1024, 0, stream>>>(staging, gcur, degi, off, csr, cap, M);
        gemm_mfma<<<(M + 63) / 64, 256, 0, stream>>>(feat, wt, h, M);  // overwrites staging
        aggregate_h<<<(M + 3) / 4, 256, 0, stream>>>(h, csr, off, degi, bias, out, M);
    } else {
        hipMemsetAsync(degi, 0, (size_t)M * sizeof(int), stream);
        hist_simple<<<(nE + 255) / 256, 256, 0, stream>>>(dst, degi, nE);
        scan_chunks<<<P, 256, 0, stream>>>(degi, off, partials, M);
        scan_partials<<<1, 256, 0, stream>>>(partials, P);
        add_base<<<(M + 255) / 256, 256, 0, stream>>>(off, cur, partials, M);
        bucket_simple<<<(nE + 255) / 256, 256, 0, stream>>>(src, dst, cur, csr, nE);
        aggregate_f32<<<(M + 3) / 4, 256, 0, stream>>>(feat, csr, off, degi, out, M);
        gemm_norm<<<(M + 63) / 64, 256, 0, stream>>>(out, weight, bias, degi, out, M);
    }
}